// Round 10
// baseline (387.244 us; speedup 1.0000x reference)
//
#include <hip/hip_runtime.h>
#include <hip/hip_bf16.h>
#include <hip/hip_fp16.h>

#define DEV __device__ __forceinline__

typedef __attribute__((ext_vector_type(8))) _Float16 h8;
typedef __attribute__((ext_vector_type(4))) float floatx4;

DEV float bf2f(unsigned short b) { return __uint_as_float(((unsigned)b) << 16); }

DEV void async_ld16(const void* g, void* l) {
  __builtin_amdgcn_global_load_lds(
      (const __attribute__((address_space(1))) unsigned int*)g,
      (__attribute__((address_space(3))) unsigned int*)l, 16, 0, 0);
}

// Fragment-linear element index: matrix [R x C] stored as 16x32 tiles in MFMA
// A/B-operand lane order. tpc = C/32.
DEV size_t fl_idx(size_t i, size_t j, int tpc) {
  return ((i >> 4) * (size_t)tpc + (j >> 5)) * 512 +
         (((i & 15) + ((j >> 3) & 3) * 16) * 8) + (j & 7);
}

// Runtime dtype probe (safety net): 1 if float tensors are bf16-packed, 0 if fp32.
DEV int detect_bf16(const void* x_mean) {
  const unsigned* w = (const unsigned*)x_mean;
  unsigned v = w[threadIdx.x & 63];
  unsigned ex = (v >> 7) & 0xFFu;
  int vote = (ex >= 100u && ex <= 144u) ? 1 : 0;
  unsigned long long b = __ballot(vote);
  return __popcll(b) >= 48 ? 1 : 0;
}

DEV float load_elem(const void* p, int isbf, size_t i) {
  return isbf ? bf2f(((const unsigned short*)p)[i]) : ((const float*)p)[i];
}

// Load 8 consecutive elements (fp32 or bf16), scale, -> 8 fp16 into LDS.
DEV void stage8h(const void* src, int isbf, size_t idx, float scale, _Float16* dst) {
  h8 o;
  if (isbf) {
    const unsigned short* s = (const unsigned short*)src + idx;
#pragma unroll
    for (int j = 0; j < 8; ++j) o[j] = (_Float16)(bf2f(s[j]) * scale);
  } else {
    const float* f = (const float*)src + idx;
    float4 a = *(const float4*)f;
    float4 b = *(const float4*)(f + 4);
    o[0] = (_Float16)(a.x * scale); o[1] = (_Float16)(a.y * scale);
    o[2] = (_Float16)(a.z * scale); o[3] = (_Float16)(a.w * scale);
    o[4] = (_Float16)(b.x * scale); o[5] = (_Float16)(b.y * scale);
    o[6] = (_Float16)(b.z * scale); o[7] = (_Float16)(b.w * scale);
  }
  *(h8*)dst = o;
}

// ---------- convert-staging 128x128 NT GEMM (K=256): C = scale*(A@B^T + bias) ----------
template <bool F32_OUT>
DEV void gemm_cvt_core(const void* A, int a_bf, const void* B, int b_bf,
                       const void* bias, int bias_bf, const float* rowdiv,
                       void* __restrict__ Cv, size_t ldc, int fl_tpc,
                       size_t i0, size_t j0, float scale, int bias_mode) {
  __shared__ __align__(16) _Float16 As[128 * 32];
  __shared__ __align__(16) _Float16 Bs[128 * 32];
  const int t = threadIdx.x;
  const int lane = t & 63, wave = t >> 6;
  const int wr = wave >> 1, wc = wave & 1;
  const int q = lane >> 4, m = lane & 15;
  floatx4 acc[4][4] = {};
  for (int k0 = 0; k0 < 256; k0 += 32) {
#pragma unroll
    for (int it = 0; it < 2; ++it) {
      int e = it * 2048 + t * 8;
      int row = e >> 5, col = e & 31;
      float asc = rowdiv ? 1.f / rowdiv[i0 + row] : 1.f;
      stage8h(A, a_bf, (i0 + row) * (size_t)256 + k0 + col, asc, &As[e]);
      stage8h(B, b_bf, (j0 + row) * (size_t)256 + k0 + col, 1.f, &Bs[e]);
    }
    __syncthreads();
    h8 af[4], bfr[4];
#pragma unroll
    for (int r = 0; r < 4; ++r)
      af[r] = *(const h8*)&As[(wr * 64 + r * 16 + m) * 32 + q * 8];
#pragma unroll
    for (int c = 0; c < 4; ++c)
      bfr[c] = *(const h8*)&Bs[(wc * 64 + c * 16 + m) * 32 + q * 8];
#pragma unroll
    for (int r = 0; r < 4; ++r)
#pragma unroll
      for (int c = 0; c < 4; ++c)
        acc[r][c] = __builtin_amdgcn_mfma_f32_16x16x32_f16(af[r], bfr[c], acc[r][c], 0, 0, 0);
    __syncthreads();
  }
#pragma unroll
  for (int r = 0; r < 4; ++r) {
#pragma unroll
    for (int c = 0; c < 4; ++c) {
      size_t col = j0 + wc * 64 + c * 16 + m;
      float bcol = (bias_mode == 0) ? load_elem(bias, bias_bf, col) : 0.f;
#pragma unroll
      for (int g = 0; g < 4; ++g) {
        size_t row = i0 + wr * 64 + r * 16 + q * 4 + g;
        float val = acc[r][c][g] + bcol;
        if (bias_mode == 1) val += load_elem(bias, bias_bf, row);
        val *= scale;
        if (F32_OUT)
          ((float*)Cv)[row * ldc + col] = val;
        else if (fl_tpc > 0)
          ((_Float16*)Cv)[fl_idx(row, col, fl_tpc)] = (_Float16)val;
        else
          ((_Float16*)Cv)[row * ldc + col] = (_Float16)val;
      }
    }
  }
}

// ---------- K1: four input projections (fp16 fragment-linear outputs to ws) ----------
struct ProjArgs {
  const void* A[4];
  const void* B[4];
  const void* bias[4];
  _Float16* C[4];
  int fl_tpc[4];
  float scale[4];
  int bias_row[4];
  const void* xdet;
};

__global__ __launch_bounds__(256) void proj_kernel(ProjArgs p) {
  int isbf = detect_bf16(p.xdet);
  int z = blockIdx.z;
  size_t i0, j0;
  if (z < 2) { i0 = (size_t)blockIdx.x * 128; j0 = (size_t)blockIdx.y * 128; }
  else       { i0 = (size_t)blockIdx.y * 128; j0 = (size_t)blockIdx.x * 128; }
  gemm_cvt_core<false>(p.A[z], isbf, p.B[z], isbf, p.bias[z], isbf, nullptr,
                       p.C[z], 0, p.fl_tpc[z], i0, j0, p.scale[z], p.bias_row[z]);
}

// ---------- K2: E = exp(q'@k^T)*2^-6, fragment-linear out + row sums ----------
// (proven Round-8 version: BK=32, 16 MFMA/barrier)
__global__ __launch_bounds__(256) void qk_exp_kernel(const _Float16* __restrict__ qb,
                                                     const _Float16* __restrict__ kb,
                                                     _Float16* __restrict__ E,
                                                     float* __restrict__ rs) {
  __shared__ __align__(16) char smem[128 * 136 * 2];  // 34816 B
  _Float16* As = (_Float16*)smem;        // 4096 elems (8 KB), k-loop only
  _Float16* Bs = As + 4096;              // 4096 elems (8 KB), k-loop only
  _Float16* Ts = (_Float16*)smem;        // 128x136 transpose buf, epilogue only
  const int t = threadIdx.x;
  const int lane = t & 63, wave = t >> 6;
  const int wr = wave >> 1, wc = wave & 1;
  const int q = lane >> 4, m = lane & 15;
  const size_t bx = blockIdx.x, by = blockIdx.y;
  const size_t i0 = bx * 128;
  floatx4 acc[4][4] = {};
  for (int kt = 0; kt < 8; ++kt) {
#pragma unroll
    for (int it = 0; it < 2; ++it) {
      int c = it * 4 + wave;  // chunk = fragment tile (1024 B)
      async_ld16(&qb[((bx * 8 + c) * 8 + kt) * 512 + lane * 8], &As[c * 512 + lane * 8]);
      async_ld16(&kb[((by * 8 + c) * 8 + kt) * 512 + lane * 8], &Bs[c * 512 + lane * 8]);
    }
    __syncthreads();
    h8 af[4], bfr[4];
#pragma unroll
    for (int r = 0; r < 4; ++r)
      af[r] = *(const h8*)&As[(wr * 4 + r) * 512 + lane * 8];
#pragma unroll
    for (int c = 0; c < 4; ++c)
      bfr[c] = *(const h8*)&Bs[(wc * 4 + c) * 512 + lane * 8];
#pragma unroll
    for (int r = 0; r < 4; ++r)
#pragma unroll
      for (int c = 0; c < 4; ++c)
        acc[r][c] = __builtin_amdgcn_mfma_f32_16x16x32_f16(af[r], bfr[c], acc[r][c], 0, 0, 0);
    __syncthreads();
  }
  // exp in place (clamp 8: E<=47, E^2<=2170 -- fp16-safe)
#pragma unroll
  for (int r = 0; r < 4; ++r)
#pragma unroll
    for (int c = 0; c < 4; ++c)
#pragma unroll
      for (int g = 0; g < 4; ++g)
        acc[r][c][g] = __expf(fminf(acc[r][c][g], 8.f)) * 0.015625f;
  // row sums
#pragma unroll
  for (int r = 0; r < 4; ++r)
#pragma unroll
    for (int g = 0; g < 4; ++g) {
      float part = acc[r][0][g] + acc[r][1][g] + acc[r][2][g] + acc[r][3][g];
      part += __shfl_xor(part, 1);
      part += __shfl_xor(part, 2);
      part += __shfl_xor(part, 4);
      part += __shfl_xor(part, 8);
      if (m == 0)
        unsafeAtomicAdd(&rs[i0 + wr * 64 + r * 16 + q * 4 + g], part);
    }
  // transpose C-layout -> fragment-linear via LDS (padded rows: 136 elems)
#pragma unroll
  for (int r = 0; r < 4; ++r)
#pragma unroll
    for (int c = 0; c < 4; ++c)
#pragma unroll
      for (int g = 0; g < 4; ++g)
        Ts[(wr * 64 + r * 16 + q * 4 + g) * 136 + wc * 64 + c * 16 + m] =
            (_Float16)acc[r][c][g];
  __syncthreads();
  // coalesced readout: 32 fragment tiles, 16 B/lane
#pragma unroll
  for (int it = 0; it < 8; ++it) {
    int cch = it * 4 + wave;
    int ci = cch >> 2, ck = cch & 3;
    int il = ci * 16 + (lane & 15);
    int jl = ck * 32 + (lane >> 4) * 8;
    h8 v = *(const h8*)&Ts[il * 136 + jl];
    *(h8*)&E[((bx * 8 + ci) * 256 + by * 4 + ck) * 512 + lane * 8] = v;
  }
}

// ---------- zero helpers ----------
__global__ __launch_bounds__(256) void zero_rs_kernel(float* __restrict__ rs) {
  rs[blockIdx.x * 256 + threadIdx.x] = 0.f;
}
__global__ __launch_bounds__(256) void zero_acc_kernel(float* __restrict__ a,
                                                       float* __restrict__ b) {
  size_t i = ((size_t)blockIdx.x * 256 + threadIdx.x) * 4;
  float4 z = {0.f, 0.f, 0.f, 0.f};
  *(float4*)(a + i) = z;
  *(float4*)(b + i) = z;
}

// ---------- K4a/K4b: m97-shaped split-K GEMM  outp += (SQ? E^2 : E) @ BT^T ----------
// Fragment-linear operands. BM=BN=128, BK=32: per wave 4 A + 4 B ds_read_b128,
// 16 MFMA -> m97's exact hot-loop ratio. acc[4][4]=64 AGPR -> 3 waves/SIMD.
// grid (64, 2, 6) = 768 blocks = exactly 3/CU; K-tiles 43/43/43/43/43/41.
template <bool SQ>
__global__ __launch_bounds__(256) void av_core(const _Float16* __restrict__ E,
                                               const _Float16* __restrict__ BT,
                                               float* __restrict__ outp) {
  __shared__ __align__(16) _Float16 As[4096];  // 8 KB: 8 row-tiles x 1 k-tile
  __shared__ __align__(16) _Float16 Bs[4096];  // 8 KB
  const int t = threadIdx.x;
  const int lane = t & 63, wave = t >> 6;
  const int wr = wave >> 1, wc = wave & 1;
  const int q = lane >> 4, m = lane & 15;
  const size_t bx = blockIdx.x, by = blockIdx.y;
  const int z = blockIdx.z;
  const int s0 = z * 43;
  const int sn = (z == 5) ? 41 : 43;
  // hoisted per-thread staging offsets (elements), advance +512 per k-tile
  size_t aoff[2], boff[2];
#pragma unroll
  for (int it = 0; it < 2; ++it) {
    int n = it * 256 + t;           // 0..511 -> tile n>>6, elem-rem n&63
    aoff[it] = ((bx * 8 + (size_t)(n >> 6)) * 256 + (size_t)s0) * 512 + (n & 63) * 8;
    boff[it] = ((by * 8 + (size_t)(n >> 6)) * 256 + (size_t)s0) * 512 + (n & 63) * 8;
  }
  floatx4 acc[4][4] = {};
  for (int kk = 0; kk < sn; ++kk) {
#pragma unroll
    for (int it = 0; it < 2; ++it) {
      async_ld16(&E[aoff[it]], &As[(it * 256 + t) * 8]);
      async_ld16(&BT[boff[it]], &Bs[(it * 256 + t) * 8]);
    }
    __syncthreads();
    h8 af[4], bfr[4];
#pragma unroll
    for (int r = 0; r < 4; ++r) {
      af[r] = *(const h8*)&As[(wr * 4 + r) * 512 + lane * 8];
      if (SQ) af[r] = af[r] * af[r];  // v_pk_mul_f16
    }
#pragma unroll
    for (int c = 0; c < 4; ++c)
      bfr[c] = *(const h8*)&Bs[(wc * 4 + c) * 512 + lane * 8];
#pragma unroll
    for (int r = 0; r < 4; ++r)
#pragma unroll
      for (int c = 0; c < 4; ++c)
        acc[r][c] = __builtin_amdgcn_mfma_f32_16x16x32_f16(af[r], bfr[c], acc[r][c], 0, 0, 0);
    __syncthreads();
#pragma unroll
    for (int it = 0; it < 2; ++it) { aoff[it] += 512; boff[it] += 512; }
  }
#pragma unroll
  for (int r = 0; r < 4; ++r)
#pragma unroll
    for (int c = 0; c < 4; ++c) {
      size_t col = by * 128 + wc * 64 + c * 16 + m;
#pragma unroll
      for (int g = 0; g < 4; ++g) {
        size_t row = bx * 128 + wr * 64 + r * 16 + q * 4 + g;
        unsafeAtomicAdd(&outp[row * 256 + col], acc[r][c][g]);
      }
    }
}

// ---------- K4c: out_var /= rs[row]^2 ----------
__global__ __launch_bounds__(256) void var_div_kernel(float* __restrict__ ov,
                                                      const float* __restrict__ rs) {
  size_t i = ((size_t)blockIdx.x * 256 + threadIdx.x) * 4;
  float inv = 1.f / rs[i >> 8];
  float s = inv * inv;
  float4 v = *(float4*)(ov + i);
  v.x *= s; v.y *= s; v.z *= s; v.w *= s;
  *(float4*)(ov + i) = v;
}

// ---------- K5: out_mean(fp32) = (otm/rs) @ Wo^T + bo ----------
__global__ __launch_bounds__(256) void final_kernel(const float* __restrict__ ot,
                                                    const void* Wo, const void* bo,
                                                    const float* __restrict__ rs,
                                                    const void* xdet,
                                                    float* __restrict__ Cm) {
  int isbf = detect_bf16(xdet);
  gemm_cvt_core<true>(ot, 0, Wo, isbf, bo, isbf, rs, Cm, 256, 0,
                      (size_t)blockIdx.x * 128, (size_t)blockIdx.y * 128, 1.f, 0);
}

extern "C" void kernel_launch(void* const* d_in, const int* in_sizes, int n_in,
                              void* d_out, int out_size, void* d_ws, size_t ws_size,
                              hipStream_t stream) {
  const void* x_mean = d_in[0];
  const void* x_var  = d_in[1];
  // d_in[2] edge_index, d_in[3] edge_timestamps: unused by the reference
  const void* Wq   = d_in[4];
  const void* bq   = d_in[5];
  const void* Wk   = d_in[6];
  const void* bk   = d_in[7];
  const void* Wv   = d_in[8];
  const void* bv   = d_in[9];
  const void* Wo   = d_in[10];
  const void* bo   = d_in[11];
  const void* Wvar = d_in[12];
  const void* bvar = d_in[13];
  float* out = (float*)d_out;  // [out_mean (8192*256) | out_var (8192*256)] fp32

  const size_t NE_S = 67108864;  // 8192*8192
  const size_t NE_P = 2097152;   // 8192*256
  if (ws_size < (NE_S + 5 * NE_P) * 2) return;  // ~155 MB scratch
  _Float16* w   = (_Float16*)d_ws;
  _Float16* S   = w;              // E = exp(logits)*2^-6, fragment-linear [8192x8192]
  _Float16* qb  = w + NE_S;       // q*0.125 (+bq), fragment-linear [8192x256]
  _Float16* kb  = qb + NE_P;      // k, fragment-linear [8192x256]
  _Float16* vT  = kb + NE_P;      // v^T, fragment-linear [256x8192]
  _Float16* vvT = vT + NE_P;      // v_var^T, fragment-linear [256x8192]
  float* rs     = (float*)(vvT + NE_P);  // row sums of E, fp32 [8192]
  // fp32 mean accumulator aliases qb+kb (dead after qk_exp): 8 MB exactly
  float* ot_f32 = (float*)qb;

  ProjArgs p;
  p.A[0] = x_mean; p.B[0] = Wq;     p.bias[0] = bq;   p.C[0] = qb;  p.fl_tpc[0] = 8;   p.scale[0] = 0.125f; p.bias_row[0] = 0;
  p.A[1] = x_mean; p.B[1] = Wk;     p.bias[1] = bk;   p.C[1] = kb;  p.fl_tpc[1] = 8;   p.scale[1] = 1.f;    p.bias_row[1] = 0;
  p.A[2] = Wv;     p.B[2] = x_mean; p.bias[2] = bv;   p.C[2] = vT;  p.fl_tpc[2] = 256; p.scale[2] = 1.f;    p.bias_row[2] = 1;
  p.A[3] = Wvar;   p.B[3] = x_var;  p.bias[3] = bvar; p.C[3] = vvT; p.fl_tpc[3] = 256; p.scale[3] = 1.f;    p.bias_row[3] = 1;
  p.xdet = x_mean;

  zero_rs_kernel<<<dim3(32), 256, 0, stream>>>(rs);
  proj_kernel<<<dim3(64, 2, 4), 256, 0, stream>>>(p);
  qk_exp_kernel<<<dim3(64, 64), 256, 0, stream>>>(qb, kb, S, rs);
  // zero AFTER qk_exp (ot_f32 overwrites qb/kb), BEFORE av
  zero_acc_kernel<<<dim3(2048), 256, 0, stream>>>(ot_f32, out + NE_P);
  av_core<false><<<dim3(64, 2, 6), 256, 0, stream>>>(S, vT, ot_f32);
  av_core<true><<<dim3(64, 2, 6), 256, 0, stream>>>(S, vvT, out + NE_P);
  var_div_kernel<<<dim3(2048), 256, 0, stream>>>(out + NE_P, rs);
  final_kernel<<<dim3(64, 2), 256, 0, stream>>>(ot_f32, Wo, bo, rs, x_mean, out);
}

// Round 11
// 322.424 us; speedup vs baseline: 1.2010x; 1.2010x over previous
//
#include <hip/hip_runtime.h>
#include <hip/hip_bf16.h>
#include <hip/hip_fp16.h>

#define DEV __device__ __forceinline__

typedef __attribute__((ext_vector_type(8))) _Float16 h8;
typedef __attribute__((ext_vector_type(4))) float floatx4;

DEV float bf2f(unsigned short b) { return __uint_as_float(((unsigned)b) << 16); }

DEV void async_ld16(const void* g, void* l) {
  __builtin_amdgcn_global_load_lds(
      (const __attribute__((address_space(1))) unsigned int*)g,
      (__attribute__((address_space(3))) unsigned int*)l, 16, 0, 0);
}

// Runtime dtype probe (safety net): 1 if float tensors are bf16-packed, 0 if fp32.
DEV int detect_bf16(const void* x_mean) {
  const unsigned* w = (const unsigned*)x_mean;
  unsigned v = w[threadIdx.x & 63];
  unsigned ex = (v >> 7) & 0xFFu;
  int vote = (ex >= 100u && ex <= 144u) ? 1 : 0;
  unsigned long long b = __ballot(vote);
  return __popcll(b) >= 48 ? 1 : 0;
}

DEV float load_elem(const void* p, int isbf, size_t i) {
  return isbf ? bf2f(((const unsigned short*)p)[i]) : ((const float*)p)[i];
}

// Load 8 consecutive elements (fp32 or bf16), scale, -> 8 fp16 into LDS.
DEV void stage8h(const void* src, int isbf, size_t idx, float scale, _Float16* dst) {
  h8 o;
  if (isbf) {
    const unsigned short* s = (const unsigned short*)src + idx;
#pragma unroll
    for (int j = 0; j < 8; ++j) o[j] = (_Float16)(bf2f(s[j]) * scale);
  } else {
    const float* f = (const float*)src + idx;
    float4 a = *(const float4*)f;
    float4 b = *(const float4*)(f + 4);
    o[0] = (_Float16)(a.x * scale); o[1] = (_Float16)(a.y * scale);
    o[2] = (_Float16)(a.z * scale); o[3] = (_Float16)(a.w * scale);
    o[4] = (_Float16)(b.x * scale); o[5] = (_Float16)(b.y * scale);
    o[6] = (_Float16)(b.z * scale); o[7] = (_Float16)(b.w * scale);
  }
  *(h8*)dst = o;
}

// ---------- K1: four input projections, 128x128 tile, K=256 ----------
// Output fp16 fragment-linear via LDS-transpose epilogue (coalesced 16B stores).
struct ProjArgs {
  const void* A[4];
  const void* B[4];
  const void* bias[4];
  _Float16* C[4];
  int fl_tpc[4];
  float scale[4];
  int bias_row[4];
  const void* xdet;
};

__global__ __launch_bounds__(256) void proj_kernel(ProjArgs p) {
  __shared__ __align__(16) char smem[34816];  // k-loop: As+Bs 16 KB; epilogue: Ts 128x136
  _Float16* As = (_Float16*)smem;
  _Float16* Bs = As + 4096;
  _Float16* Ts = (_Float16*)smem;
  int isbf = detect_bf16(p.xdet);
  int z = blockIdx.z;
  size_t i0, j0;
  if (z < 2) { i0 = (size_t)blockIdx.x * 128; j0 = (size_t)blockIdx.y * 128; }
  else       { i0 = (size_t)blockIdx.y * 128; j0 = (size_t)blockIdx.x * 128; }
  const void* A = p.A[z];
  const void* B = p.B[z];
  const void* bias = p.bias[z];
  const float scale = p.scale[z];
  const int bias_row = p.bias_row[z];
  const int tpc = p.fl_tpc[z];
  _Float16* C = p.C[z];
  const int t = threadIdx.x;
  const int lane = t & 63, wave = t >> 6;
  const int wr = wave >> 1, wc = wave & 1;
  const int q = lane >> 4, m = lane & 15;
  floatx4 acc[4][4] = {};
  for (int k0 = 0; k0 < 256; k0 += 32) {
#pragma unroll
    for (int it = 0; it < 2; ++it) {
      int e = it * 2048 + t * 8;
      int row = e >> 5, col = e & 31;
      stage8h(A, isbf, (i0 + row) * (size_t)256 + k0 + col, 1.f, &As[e]);
      stage8h(B, isbf, (j0 + row) * (size_t)256 + k0 + col, 1.f, &Bs[e]);
    }
    __syncthreads();
    h8 af[4], bfr[4];
#pragma unroll
    for (int r = 0; r < 4; ++r)
      af[r] = *(const h8*)&As[(wr * 64 + r * 16 + m) * 32 + q * 8];
#pragma unroll
    for (int c = 0; c < 4; ++c)
      bfr[c] = *(const h8*)&Bs[(wc * 64 + c * 16 + m) * 32 + q * 8];
#pragma unroll
    for (int r = 0; r < 4; ++r)
#pragma unroll
      for (int c = 0; c < 4; ++c)
        acc[r][c] = __builtin_amdgcn_mfma_f32_16x16x32_f16(af[r], bfr[c], acc[r][c], 0, 0, 0);
    __syncthreads();
  }
  // bias + scale, into LDS transpose buffer
#pragma unroll
  for (int r = 0; r < 4; ++r)
#pragma unroll
    for (int c = 0; c < 4; ++c) {
      size_t col = j0 + wc * 64 + c * 16 + m;
      float bcol = bias_row ? 0.f : load_elem(bias, isbf, col);
#pragma unroll
      for (int g = 0; g < 4; ++g) {
        size_t row = i0 + wr * 64 + r * 16 + q * 4 + g;
        float val = acc[r][c][g] + bcol;
        if (bias_row) val += load_elem(bias, isbf, row);
        Ts[(wr * 64 + r * 16 + q * 4 + g) * 136 + wc * 64 + c * 16 + m] =
            (_Float16)(val * scale);
      }
    }
  __syncthreads();
  // coalesced fragment-linear writeout: 32 tiles, 16 B/lane
  size_t ti0 = i0 >> 4, tj0 = j0 >> 5;
#pragma unroll
  for (int it = 0; it < 8; ++it) {
    int cch = it * 4 + wave;
    int ci = cch >> 2, ck = cch & 3;
    int il = ci * 16 + (lane & 15);
    int jl = ck * 32 + (lane >> 4) * 8;
    h8 v = *(const h8*)&Ts[il * 136 + jl];
    *(h8*)&C[((ti0 + ci) * (size_t)tpc + (tj0 + ck)) * 512 + lane * 8] = v;
  }
}

// ---------- K2: E = exp(q'@k^T)*2^-6, fragment-linear out + row sums ----------
// (proven R8 version, untouched: 91 us)
__global__ __launch_bounds__(256) void qk_exp_kernel(const _Float16* __restrict__ qb,
                                                     const _Float16* __restrict__ kb,
                                                     _Float16* __restrict__ E,
                                                     float* __restrict__ rs) {
  __shared__ __align__(16) char smem[128 * 136 * 2];  // 34816 B
  _Float16* As = (_Float16*)smem;
  _Float16* Bs = As + 4096;
  _Float16* Ts = (_Float16*)smem;
  const int t = threadIdx.x;
  const int lane = t & 63, wave = t >> 6;
  const int wr = wave >> 1, wc = wave & 1;
  const int q = lane >> 4, m = lane & 15;
  const size_t bx = blockIdx.x, by = blockIdx.y;
  const size_t i0 = bx * 128;
  floatx4 acc[4][4] = {};
  for (int kt = 0; kt < 8; ++kt) {
#pragma unroll
    for (int it = 0; it < 2; ++it) {
      int c = it * 4 + wave;
      async_ld16(&qb[((bx * 8 + c) * 8 + kt) * 512 + lane * 8], &As[c * 512 + lane * 8]);
      async_ld16(&kb[((by * 8 + c) * 8 + kt) * 512 + lane * 8], &Bs[c * 512 + lane * 8]);
    }
    __syncthreads();
    h8 af[4], bfr[4];
#pragma unroll
    for (int r = 0; r < 4; ++r)
      af[r] = *(const h8*)&As[(wr * 4 + r) * 512 + lane * 8];
#pragma unroll
    for (int c = 0; c < 4; ++c)
      bfr[c] = *(const h8*)&Bs[(wc * 4 + c) * 512 + lane * 8];
#pragma unroll
    for (int r = 0; r < 4; ++r)
#pragma unroll
      for (int c = 0; c < 4; ++c)
        acc[r][c] = __builtin_amdgcn_mfma_f32_16x16x32_f16(af[r], bfr[c], acc[r][c], 0, 0, 0);
    __syncthreads();
  }
#pragma unroll
  for (int r = 0; r < 4; ++r)
#pragma unroll
    for (int c = 0; c < 4; ++c)
#pragma unroll
      for (int g = 0; g < 4; ++g)
        acc[r][c][g] = __expf(fminf(acc[r][c][g], 8.f)) * 0.015625f;
#pragma unroll
  for (int r = 0; r < 4; ++r)
#pragma unroll
    for (int g = 0; g < 4; ++g) {
      float part = acc[r][0][g] + acc[r][1][g] + acc[r][2][g] + acc[r][3][g];
      part += __shfl_xor(part, 1);
      part += __shfl_xor(part, 2);
      part += __shfl_xor(part, 4);
      part += __shfl_xor(part, 8);
      if (m == 0)
        unsafeAtomicAdd(&rs[i0 + wr * 64 + r * 16 + q * 4 + g], part);
    }
#pragma unroll
  for (int r = 0; r < 4; ++r)
#pragma unroll
    for (int c = 0; c < 4; ++c)
#pragma unroll
      for (int g = 0; g < 4; ++g)
        Ts[(wr * 64 + r * 16 + q * 4 + g) * 136 + wc * 64 + c * 16 + m] =
            (_Float16)acc[r][c][g];
  __syncthreads();
#pragma unroll
  for (int it = 0; it < 8; ++it) {
    int cch = it * 4 + wave;
    int ci = cch >> 2, ck = cch & 3;
    int il = ci * 16 + (lane & 15);
    int jl = ck * 32 + (lane >> 4) * 8;
    h8 v = *(const h8*)&Ts[il * 136 + jl];
    *(h8*)&E[((bx * 8 + ci) * 256 + by * 4 + ck) * 512 + lane * 8] = v;
  }
}

// ---------- zero helpers ----------
__global__ __launch_bounds__(256) void zero_rs_kernel(float* __restrict__ rs) {
  rs[blockIdx.x * 256 + threadIdx.x] = 0.f;
}
__global__ __launch_bounds__(256) void zero_acc_kernel(float* __restrict__ a,
                                                       float* __restrict__ b) {
  size_t i = ((size_t)blockIdx.x * 256 + threadIdx.x) * 4;
  float4 z = {0.f, 0.f, 0.f, 0.f};
  *(float4*)(a + i) = z;
  *(float4*)(b + i) = z;
}

// ---------- K4: fused split-K  otm += (E@v^T)/rs, otv += (E^2@v_var^T)/rs^2 ----------
// R8's proven 132-us structure (BM=64, BN=128, BK=32, 20 KB LDS, split-K 3)
// + launch_bounds(256,4) for 4 waves/SIMD + hoisted offsets + rs-fold epilogue.
__global__ __launch_bounds__(256, 4) void av_fused(const _Float16* __restrict__ E,
                                                   const _Float16* __restrict__ vT,
                                                   const _Float16* __restrict__ vvT,
                                                   const float* __restrict__ rs,
                                                   float* __restrict__ otm,
                                                   float* __restrict__ otv) {
  __shared__ __align__(16) _Float16 As[4 * 512];    // 4 KB
  __shared__ __align__(16) _Float16 B1s[8 * 512];   // 8 KB
  __shared__ __align__(16) _Float16 B2s[8 * 512];   // 8 KB
  const int t = threadIdx.x;
  const int lane = t & 63, wave = t >> 6;
  const int wr = wave >> 1, wc = wave & 1;
  const int q = lane >> 4, m = lane & 15;
  const size_t bx = blockIdx.x, by = blockIdx.y;
  const int kt0 = (blockIdx.z == 0) ? 0 : 86 + (blockIdx.z - 1) * 85;
  const int ktn = (blockIdx.z == 0) ? 86 : 85;
  // hoisted staging offsets (elements), advance +512 per k-tile
  size_t aoff = ((bx * 4 + (size_t)wave) * 256 + (size_t)kt0) * 512 + lane * 8;
  size_t boff0 = ((by * 8 + (size_t)wave) * 256 + (size_t)kt0) * 512 + lane * 8;
  size_t boff1 = ((by * 8 + (size_t)wave + 4) * 256 + (size_t)kt0) * 512 + lane * 8;
  floatx4 accm[2][4] = {}, accv[2][4] = {};
  for (int kk = 0; kk < ktn; ++kk) {
    async_ld16(&E[aoff], &As[wave * 512 + lane * 8]);
    async_ld16(&vT[boff0], &B1s[wave * 512 + lane * 8]);
    async_ld16(&vT[boff1], &B1s[(wave + 4) * 512 + lane * 8]);
    async_ld16(&vvT[boff0], &B2s[wave * 512 + lane * 8]);
    async_ld16(&vvT[boff1], &B2s[(wave + 4) * 512 + lane * 8]);
    __syncthreads();
    h8 a[2], a2[2], b1[4], b2[4];
#pragma unroll
    for (int r = 0; r < 2; ++r) {
      a[r] = *(const h8*)&As[(wr * 2 + r) * 512 + lane * 8];
      a2[r] = a[r] * a[r];  // v_pk_mul_f16
    }
#pragma unroll
    for (int c = 0; c < 4; ++c) {
      b1[c] = *(const h8*)&B1s[(wc * 4 + c) * 512 + lane * 8];
      b2[c] = *(const h8*)&B2s[(wc * 4 + c) * 512 + lane * 8];
    }
#pragma unroll
    for (int r = 0; r < 2; ++r)
#pragma unroll
      for (int c = 0; c < 4; ++c) {
        accm[r][c] = __builtin_amdgcn_mfma_f32_16x16x32_f16(a[r], b1[c], accm[r][c], 0, 0, 0);
        accv[r][c] = __builtin_amdgcn_mfma_f32_16x16x32_f16(a2[r], b2[c], accv[r][c], 0, 0, 0);
      }
    __syncthreads();
    aoff += 512; boff0 += 512; boff1 += 512;
  }
  // epilogue: normalize by rs (commutes with split-K sum), atomic accumulate
#pragma unroll
  for (int r = 0; r < 2; ++r)
#pragma unroll
    for (int g = 0; g < 4; ++g) {
      size_t row = bx * 64 + wr * 32 + r * 16 + q * 4 + g;
      float inv = 1.f / rs[row];
      float inv2 = inv * inv;
#pragma unroll
      for (int c = 0; c < 4; ++c) {
        size_t col = by * 128 + wc * 64 + c * 16 + m;
        unsafeAtomicAdd(&otm[row * 256 + col], accm[r][c][g] * inv);
        unsafeAtomicAdd(&otv[row * 256 + col], accv[r][c][g] * inv2);
      }
    }
}

// ---------- K5: out_mean(fp32) = otm @ Wo^T + bo.  BM=64, BN=128, grid (128,2) ----------
__global__ __launch_bounds__(256) void final_kernel(const float* __restrict__ ot,
                                                    const void* Wo, const void* bo,
                                                    const void* xdet,
                                                    float* __restrict__ Cm) {
  __shared__ __align__(16) _Float16 As[64 * 32];    // 4 KB
  __shared__ __align__(16) _Float16 Bs[128 * 32];   // 8 KB
  int isbf = detect_bf16(xdet);
  const int t = threadIdx.x;
  const int lane = t & 63, wave = t >> 6;
  const int wr = wave >> 1, wc = wave & 1;
  const int q = lane >> 4, m = lane & 15;
  const size_t i0 = (size_t)blockIdx.x * 64, j0 = (size_t)blockIdx.y * 128;
  floatx4 acc[2][4] = {};
  for (int k0 = 0; k0 < 256; k0 += 32) {
    {
      int e = t * 8;
      int row = e >> 5, col = e & 31;
      stage8h(ot, 0, (i0 + row) * (size_t)256 + k0 + col, 1.f, &As[e]);
    }
#pragma unroll
    for (int it = 0; it < 2; ++it) {
      int e = it * 2048 + t * 8;
      int row = e >> 5, col = e & 31;
      stage8h(Wo, isbf, (j0 + row) * (size_t)256 + k0 + col, 1.f, &Bs[e]);
    }
    __syncthreads();
    h8 af[2], bfr[4];
#pragma unroll
    for (int r = 0; r < 2; ++r)
      af[r] = *(const h8*)&As[(wr * 32 + r * 16 + m) * 32 + q * 8];
#pragma unroll
    for (int c = 0; c < 4; ++c)
      bfr[c] = *(const h8*)&Bs[(wc * 64 + c * 16 + m) * 32 + q * 8];
#pragma unroll
    for (int r = 0; r < 2; ++r)
#pragma unroll
      for (int c = 0; c < 4; ++c)
        acc[r][c] = __builtin_amdgcn_mfma_f32_16x16x32_f16(af[r], bfr[c], acc[r][c], 0, 0, 0);
    __syncthreads();
  }
#pragma unroll
  for (int r = 0; r < 2; ++r)
#pragma unroll
    for (int c = 0; c < 4; ++c) {
      size_t col = j0 + wc * 64 + c * 16 + m;
      float bcol = load_elem(bo, isbf, col);
#pragma unroll
      for (int g = 0; g < 4; ++g) {
        size_t row = i0 + wr * 32 + r * 16 + q * 4 + g;
        Cm[row * 256 + col] = acc[r][c][g] + bcol;
      }
    }
}

extern "C" void kernel_launch(void* const* d_in, const int* in_sizes, int n_in,
                              void* d_out, int out_size, void* d_ws, size_t ws_size,
                              hipStream_t stream) {
  const void* x_mean = d_in[0];
  const void* x_var  = d_in[1];
  // d_in[2] edge_index, d_in[3] edge_timestamps: unused by the reference
  const void* Wq   = d_in[4];
  const void* bq   = d_in[5];
  const void* Wk   = d_in[6];
  const void* bk   = d_in[7];
  const void* Wv   = d_in[8];
  const void* bv   = d_in[9];
  const void* Wo   = d_in[10];
  const void* bo   = d_in[11];
  const void* Wvar = d_in[12];
  const void* bvar = d_in[13];
  float* out = (float*)d_out;  // [out_mean (8192*256) | out_var (8192*256)] fp32

  const size_t NE_S = 67108864;  // 8192*8192
  const size_t NE_P = 2097152;   // 8192*256
  if (ws_size < (NE_S + 5 * NE_P) * 2) return;  // ~155 MB scratch
  _Float16* w   = (_Float16*)d_ws;
  _Float16* S   = w;              // E = exp(logits)*2^-6, fragment-linear [8192x8192]
  _Float16* qb  = w + NE_S;       // q*0.125 (+bq), fragment-linear [8192x256]
  _Float16* kb  = qb + NE_P;      // k, fragment-linear [8192x256]
  _Float16* vT  = kb + NE_P;      // v^T, fragment-linear [256x8192]
  _Float16* vvT = vT + NE_P;      // v_var^T, fragment-linear [256x8192]
  float* rs     = (float*)(vvT + NE_P);  // row sums of E, fp32 [8192]
  // fp32 mean accumulator aliases qb+kb (dead after qk_exp): 8 MB exactly
  float* ot_f32 = (float*)qb;

  ProjArgs p;
  p.A[0] = x_mean; p.B[0] = Wq;     p.bias[0] = bq;   p.C[0] = qb;  p.fl_tpc[0] = 8;   p.scale[0] = 0.125f; p.bias_row[0] = 0;
  p.A[1] = x_mean; p.B[1] = Wk;     p.bias[1] = bk;   p.C[1] = kb;  p.fl_tpc[1] = 8;   p.scale[1] = 1.f;    p.bias_row[1] = 0;
  p.A[2] = Wv;     p.B[2] = x_mean; p.bias[2] = bv;   p.C[2] = vT;  p.fl_tpc[2] = 256; p.scale[2] = 1.f;    p.bias_row[2] = 1;
  p.A[3] = Wvar;   p.B[3] = x_var;  p.bias[3] = bvar; p.C[3] = vvT; p.fl_tpc[3] = 256; p.scale[3] = 1.f;    p.bias_row[3] = 1;
  p.xdet = x_mean;

  zero_rs_kernel<<<dim3(32), 256, 0, stream>>>(rs);
  proj_kernel<<<dim3(64, 2, 4), 256, 0, stream>>>(p);
  qk_exp_kernel<<<dim3(64, 64), 256, 0, stream>>>(qb, kb, S, rs);
  // zero AFTER qk_exp (ot_f32 overwrites qb/kb), BEFORE av
  zero_acc_kernel<<<dim3(2048), 256, 0, stream>>>(ot_f32, out + NE_P);
  av_fused<<<dim3(128, 2, 3), 256, 0, stream>>>(S, vT, vvT, rs, ot_f32, out + NE_P);
  final_kernel<<<dim3(128, 2), 256, 0, stream>>>(ot_f32, Wo, bo, x_mean, out);
}